// Round 4
// baseline (194.430 us; speedup 1.0000x reference)
//
#include <hip/hip_runtime.h>

#define BB 16
#define SS 64
#define HH 16
#define DD 16
#define EE 256
#define HIDD 128
#define RA 8   // rows per block in kA
#define RC 8   // rows per block in kC

typedef float f32x4 __attribute__((ext_vector_type(4)));

#define K2CONST 2.8853900817779268f  /* 2*log2(e) */

// ---------------- Kernel A: q/k/v projections + scaled additive pre terms ---
// grid = B*S/RA = 128, block = 768. Thread t: which = t>>8 (0=q,1=k,2=v),
// col = t&255 -> computes that output column for RA rows.
__global__ __launch_bounds__(768) void kA(
    const float* __restrict__ x,
    const float* __restrict__ Wq, const float* __restrict__ bq,
    const float* __restrict__ Wk, const float* __restrict__ bk,
    const float* __restrict__ Wv, const float* __restrict__ bv,
    const float* __restrict__ Wa, const float* __restrict__ ba,
    float* __restrict__ v_ws, float* __restrict__ preq_ws,
    float* __restrict__ prek_ws)
{
  __shared__ float x_l[RA][EE];
  __shared__ float q_l[RA][EE];
  __shared__ float k_l[RA][EE];
  __shared__ float wa_l[HIDD][33];  // padded: bank (33c+d)%32 = (c+d)%32
  __shared__ float ba_l[HIDD];
  const int t = threadIdx.x;
  const int row0 = blockIdx.x * RA;

  for (int idx = t; idx < RA * EE; idx += 768)
    x_l[idx >> 8][idx & 255] = x[(size_t)(row0 + (idx >> 8)) * EE + (idx & 255)];
  for (int idx = t; idx < HIDD * 2 * DD; idx += 768)
    wa_l[idx >> 5][idx & 31] = Wa[idx];
  if (t < HIDD) ba_l[t] = ba[t];
  __syncthreads();

  const int which = t >> 8;
  const int col = t & 255;
  const float* Wrow = (which == 0 ? Wq : (which == 1 ? Wk : Wv)) + (size_t)col * EE;
  const float bias = (which == 0 ? bq : (which == 1 ? bk : bv))[col];

  float acc[RA];
#pragma unroll
  for (int r = 0; r < RA; ++r) acc[r] = 0.f;
  for (int e = 0; e < EE; e += 4) {
    const f32x4 w4 = *(const f32x4*)(Wrow + e);
#pragma unroll
    for (int r = 0; r < RA; ++r) {
      const f32x4 x4 = *(const f32x4*)&x_l[r][e];
      acc[r] += x4[0] * w4[0] + x4[1] * w4[1] + x4[2] * w4[2] + x4[3] * w4[3];
    }
  }
#pragma unroll
  for (int r = 0; r < RA; ++r) {
    const float val = acc[r] + bias;
    if (which == 0)      q_l[r][col] = val;
    else if (which == 1) k_l[r][col] = val;
    else                 v_ws[(size_t)(row0 + r) * EE + col] = val;
  }
  __syncthreads();

  // pre_q[r,h,c] = K2*(sum_d q[r,h*16+d]*Wa[c,d] + ba[c])
  // pre_k[r,h,c] = K2*(sum_d k[r,h*16+d]*Wa[c,16+d])
  for (int idx = t; idx < RA * HH * HIDD; idx += 768) {
    const int r = idx >> 11;
    const int h = (idx >> 7) & 15;
    const int c = idx & 127;
    float sq = ba_l[c];
    float sk = 0.f;
#pragma unroll
    for (int d = 0; d < DD; ++d) {
      const float qd = q_l[r][h * DD + d];
      const float kd = k_l[r][h * DD + d];
      sq += qd * wa_l[c][d];
      sk += kd * wa_l[c][DD + d];
    }
    const size_t o = ((size_t)(row0 + r) * HH + h) * HIDD + c;
    preq_ws[o] = K2CONST * sq;
    prek_ws[o] = K2CONST * sk;
  }
}

// ---------------- Kernel B: scores (tanh dot) + softmax over j --------------
// grid = B*H = 256, block = 1024. Thread: i = t&63 (query row), g = t>>6,
// keys j = 4g..4g+3. score'(i,j) = -sum_c 2*av_c * rcp(exp2(pq+pk)+1)
// (the +sum_c av_c constant is softmax-invariant and dropped).
__global__ __launch_bounds__(1024) void kB(
    const float* __restrict__ preq_ws, const float* __restrict__ prek_ws,
    const float* __restrict__ attnv, float* __restrict__ w_ws)
{
  __shared__ float pqT[HIDD][SS + 1];  // [c][i], stride 65 -> conflict-free scalar reads
  __shared__ float pk_l[SS][HIDD];     // [j][c], reads wave-uniform
  __shared__ float s_l[SS][SS + 1];
  __shared__ float av2[HIDD];
  const int t = threadIdx.x;
  const int bid = blockIdx.x;  // b*H + h
  const int b = bid >> 4;
  const int h = bid & (HH - 1);

  const float* pqg = preq_ws + ((size_t)b * SS * HH + h) * HIDD;
  const float* pkg = prek_ws + ((size_t)b * SS * HH + h) * HIDD;
  for (int idx = t; idx < SS * 32; idx += 1024) {
    const int ii = idx >> 5;
    const int c4 = (idx & 31) << 2;
    const f32x4 vq = *(const f32x4*)(pqg + (size_t)ii * HH * HIDD + c4);
    const f32x4 vk = *(const f32x4*)(pkg + (size_t)ii * HH * HIDD + c4);
    *(f32x4*)&pk_l[ii][c4] = vk;
    pqT[c4 + 0][ii] = vq[0];
    pqT[c4 + 1][ii] = vq[1];
    pqT[c4 + 2][ii] = vq[2];
    pqT[c4 + 3][ii] = vq[3];
  }
  if (t < HIDD) av2[t] = 2.0f * attnv[t];
  __syncthreads();

  const int i = t & 63;
  const int g = t >> 6;
  const int j0 = g << 2;
  float acc0 = 0.f, acc1 = 0.f, acc2 = 0.f, acc3 = 0.f;
  for (int c = 0; c < HIDD; c += 4) {
    const float q0 = pqT[c + 0][i];
    const float q1 = pqT[c + 1][i];
    const float q2 = pqT[c + 2][i];
    const float q3 = pqT[c + 3][i];
    const f32x4 a4 = *(const f32x4*)&av2[c];
    const f32x4 k0 = *(const f32x4*)&pk_l[j0 + 0][c];
    const f32x4 k1 = *(const f32x4*)&pk_l[j0 + 1][c];
    const f32x4 k2 = *(const f32x4*)&pk_l[j0 + 2][c];
    const f32x4 k3 = *(const f32x4*)&pk_l[j0 + 3][c];
#pragma unroll
    for (int u = 0; u < 4; ++u) {
      const float qv = (u == 0 ? q0 : (u == 1 ? q1 : (u == 2 ? q2 : q3)));
      const float avu = a4[u];
      acc0 = fmaf(avu, __builtin_amdgcn_rcpf(__builtin_amdgcn_exp2f(qv + k0[u]) + 1.f), acc0);
      acc1 = fmaf(avu, __builtin_amdgcn_rcpf(__builtin_amdgcn_exp2f(qv + k1[u]) + 1.f), acc1);
      acc2 = fmaf(avu, __builtin_amdgcn_rcpf(__builtin_amdgcn_exp2f(qv + k2[u]) + 1.f), acc2);
      acc3 = fmaf(avu, __builtin_amdgcn_rcpf(__builtin_amdgcn_exp2f(qv + k3[u]) + 1.f), acc3);
    }
  }
  s_l[i][j0 + 0] = -acc0;
  s_l[i][j0 + 1] = -acc1;
  s_l[i][j0 + 2] = -acc2;
  s_l[i][j0 + 3] = -acc3;
  __syncthreads();

  // softmax over j, 16 threads per row
  const int ri = t >> 4;
  const int l16 = t & 15;
  const float v0 = s_l[ri][l16];
  const float v1 = s_l[ri][l16 + 16];
  const float v2 = s_l[ri][l16 + 32];
  const float v3 = s_l[ri][l16 + 48];
  float m = fmaxf(fmaxf(v0, v1), fmaxf(v2, v3));
#pragma unroll
  for (int o = 8; o >= 1; o >>= 1) m = fmaxf(m, __shfl_xor(m, o, 16));
  const float L2E = 1.4426950408889634f;
  const float p0 = __builtin_amdgcn_exp2f((v0 - m) * L2E);
  const float p1 = __builtin_amdgcn_exp2f((v1 - m) * L2E);
  const float p2 = __builtin_amdgcn_exp2f((v2 - m) * L2E);
  const float p3 = __builtin_amdgcn_exp2f((v3 - m) * L2E);
  float sum = p0 + p1 + p2 + p3;
#pragma unroll
  for (int o = 8; o >= 1; o >>= 1) sum += __shfl_xor(sum, o, 16);
  const float rs = __builtin_amdgcn_rcpf(sum);
  float* wrow = w_ws + ((size_t)bid * SS + ri) * SS;  // [b][h][i][j]
  wrow[l16] = p0 * rs;
  wrow[l16 + 16] = p1 * rs;
  wrow[l16 + 32] = p2 * rs;
  wrow[l16 + 48] = p3 * rs;
}

// ---------------- Kernel C: ctx (contract heads) + final GEMV ---------------
// grid = B*S/RC = 128, block = 512. Thread: e = t&255, half = t>>8 (m-split).
__global__ __launch_bounds__(512) void kC(
    const float* __restrict__ w_ws, const float* __restrict__ v_ws,
    const float* __restrict__ Wfc, const float* __restrict__ bfc,
    float* __restrict__ out)
{
  __shared__ float w_l[RC][HH * SS];    // [r][h*64+j]
  __shared__ float v_l[RC][EE];         // [r][h*16+d]
  __shared__ float ctx_l[RC][SS * DD];  // [r][j*16+d]
  __shared__ float red[RC][EE];
  const int t = threadIdx.x;
  const int row0 = blockIdx.x * RC;

  for (int r = 0; r < RC; ++r) {
    const int row = row0 + r;
    const int b = row >> 6;
    const int i = row & 63;
    const float* wsrc = w_ws + (size_t)b * HH * SS * SS + (size_t)i * SS;
    for (int idx = t; idx < HH * SS; idx += 512) {
      const int hh = idx >> 6;
      const int j = idx & 63;
      w_l[r][idx] = wsrc[(size_t)hh * SS * SS + j];
    }
    if (t < EE) v_l[r][t] = v_ws[(size_t)row * EE + t];
  }
  __syncthreads();

  // ctx[r][j*16+d] = sum_h w[r][h*64+j] * v[r][h*16+d]
  for (int idx = t; idx < RC * SS * DD; idx += 512) {
    const int r = idx >> 10;
    const int jd = idx & 1023;
    const int j = jd >> 4;
    const int d = jd & 15;
    float s = 0.f;
#pragma unroll
    for (int hh = 0; hh < HH; ++hh) s += w_l[r][hh * SS + j] * v_l[r][hh * DD + d];
    ctx_l[r][jd] = s;
  }
  __syncthreads();

  const int e = t & 255;
  const int half = t >> 8;
  const float* wf = Wfc + (size_t)e * (SS * DD) + half * 512;
  float acc[RC];
#pragma unroll
  for (int r = 0; r < RC; ++r) acc[r] = 0.f;
  for (int mm = 0; mm < 512; mm += 4) {
    const f32x4 w4 = *(const f32x4*)(wf + mm);
#pragma unroll
    for (int r = 0; r < RC; ++r) {
      const f32x4 c4 = *(const f32x4*)&ctx_l[r][half * 512 + mm];
      acc[r] += c4[0] * w4[0] + c4[1] * w4[1] + c4[2] * w4[2] + c4[3] * w4[3];
    }
  }
  if (half == 1) {
#pragma unroll
    for (int r = 0; r < RC; ++r) red[r][e] = acc[r];
  }
  __syncthreads();
  if (half == 0) {
    const float bias = bfc[e];
#pragma unroll
    for (int r = 0; r < RC; ++r)
      out[(size_t)(row0 + r) * EE + e] = acc[r] + red[r][e] + bias;
  }
}

extern "C" void kernel_launch(void* const* d_in, const int* in_sizes, int n_in,
                              void* d_out, int out_size, void* d_ws, size_t ws_size,
                              hipStream_t stream) {
  const float* x   = (const float*)d_in[0];
  const float* Wq  = (const float*)d_in[1];
  const float* bq  = (const float*)d_in[2];
  const float* Wk  = (const float*)d_in[3];
  const float* bk  = (const float*)d_in[4];
  const float* Wv  = (const float*)d_in[5];
  const float* bv  = (const float*)d_in[6];
  const float* Wa  = (const float*)d_in[7];
  const float* ba  = (const float*)d_in[8];
  const float* av  = (const float*)d_in[9];
  const float* Wfc = (const float*)d_in[10];
  const float* bfc = (const float*)d_in[11];

  float* ws = (float*)d_ws;
  float* v_ws    = ws;                                      // 262144 f32
  float* preq_ws = v_ws + (size_t)BB * SS * EE;             // 2097152 f32
  float* prek_ws = preq_ws + (size_t)BB * SS * HH * HIDD;   // 2097152 f32
  float* w_ws    = prek_ws + (size_t)BB * SS * HH * HIDD;   // 1048576 f32

  hipLaunchKernelGGL(kA, dim3(BB * SS / RA), dim3(768), 0, stream,
                     x, Wq, bq, Wk, bk, Wv, bv, Wa, ba, v_ws, preq_ws, prek_ws);
  hipLaunchKernelGGL(kB, dim3(BB * HH), dim3(1024), 0, stream,
                     preq_ws, prek_ws, av, w_ws);
  hipLaunchKernelGGL(kC, dim3(BB * SS / RC), dim3(512), 0, stream,
                     w_ws, v_ws, Wfc, bfc, (float*)d_out);
}

// Round 6
// 181.142 us; speedup vs baseline: 1.0734x; 1.0734x over previous
//
#include <hip/hip_runtime.h>

#define BB 16
#define SS 64
#define HH 16
#define DD 16
#define EE 256
#define HIDD 128
#define RA 4   // rows per block in kA (grid = 256)
#define RC 4   // rows per block in kC (grid = 256)

typedef float f32x4 __attribute__((ext_vector_type(4)));

#define K2CONST 2.8853900817779268f  /* 2*log2(e) */

// ---------------- Kernel A: q/k/v projections + scaled additive pre terms ---
// grid = B*S/RA = 256, block = 768. Thread t: which = t>>8 (0=q,1=k,2=v),
// col = t&255 -> computes that output column for RA rows.
__global__ __launch_bounds__(768) void kA(
    const float* __restrict__ x,
    const float* __restrict__ Wq, const float* __restrict__ bq,
    const float* __restrict__ Wk, const float* __restrict__ bk,
    const float* __restrict__ Wv, const float* __restrict__ bv,
    const float* __restrict__ Wa, const float* __restrict__ ba,
    float* __restrict__ v_ws, float* __restrict__ preq_ws,
    float* __restrict__ prek_ws)
{
  __shared__ float x_l[RA][EE];
  __shared__ float q_l[RA][EE];
  __shared__ float k_l[RA][EE];
  __shared__ float wa_l[HIDD][33];  // padded: bank (33c+d)%32 = (c+d)%32
  __shared__ float ba_l[HIDD];
  const int t = threadIdx.x;
  const int row0 = blockIdx.x * RA;

  for (int idx = t; idx < RA * EE; idx += 768)
    x_l[idx >> 8][idx & 255] = x[(size_t)(row0 + (idx >> 8)) * EE + (idx & 255)];
  for (int idx = t; idx < HIDD * 2 * DD; idx += 768)
    wa_l[idx >> 5][idx & 31] = Wa[idx];
  if (t < HIDD) ba_l[t] = ba[t];
  __syncthreads();

  const int which = t >> 8;
  const int col = t & 255;
  const float* Wrow = (which == 0 ? Wq : (which == 1 ? Wk : Wv)) + (size_t)col * EE;
  const float bias = (which == 0 ? bq : (which == 1 ? bk : bv))[col];

  float acc[RA];
#pragma unroll
  for (int r = 0; r < RA; ++r) acc[r] = 0.f;
  for (int e = 0; e < EE; e += 4) {
    const f32x4 w4 = *(const f32x4*)(Wrow + e);
#pragma unroll
    for (int r = 0; r < RA; ++r) {
      const f32x4 x4 = *(const f32x4*)&x_l[r][e];
      acc[r] += x4[0] * w4[0] + x4[1] * w4[1] + x4[2] * w4[2] + x4[3] * w4[3];
    }
  }
#pragma unroll
  for (int r = 0; r < RA; ++r) {
    const float val = acc[r] + bias;
    if (which == 0)      q_l[r][col] = val;
    else if (which == 1) k_l[r][col] = val;
    else                 v_ws[(size_t)(row0 + r) * EE + col] = val;
  }
  __syncthreads();

  // pre_q[r,h,c] = K2*(sum_d q[r,h*16+d]*Wa[c,d] + ba[c])
  // pre_k[r,h,c] = K2*(sum_d k[r,h*16+d]*Wa[c,16+d])
  for (int idx = t; idx < RA * HH * HIDD; idx += 768) {
    const int r = idx >> 11;
    const int h = (idx >> 7) & 15;
    const int c = idx & 127;
    float sq = ba_l[c];
    float sk = 0.f;
#pragma unroll
    for (int d = 0; d < DD; ++d) {
      const float qd = q_l[r][h * DD + d];
      const float kd = k_l[r][h * DD + d];
      sq += qd * wa_l[c][d];
      sk += kd * wa_l[c][DD + d];
    }
    const size_t o = ((size_t)(row0 + r) * HH + h) * HIDD + c;
    preq_ws[o] = K2CONST * sq;
    prek_ws[o] = K2CONST * sk;
  }
}

// ---------------- Kernel B: scores (tanh dot) + softmax over j --------------
// grid = B*H = 256, block = 1024. Thread: i = t&63 (query row), g = t>>6,
// keys j = 4g..4g+3. score'(i,j) = -sum_c 2*av_c * rcp(exp2(pq+pk)+1)
// (the +sum_c av_c constant is softmax-invariant and dropped).
__global__ __launch_bounds__(1024) void kB(
    const float* __restrict__ preq_ws, const float* __restrict__ prek_ws,
    const float* __restrict__ attnv, float* __restrict__ w_ws)
{
  __shared__ float pqT[HIDD][SS + 1];  // [c][i], stride 65 -> conflict-free scalar reads
  __shared__ float pk_l[SS][HIDD];     // [j][c], reads wave-uniform
  __shared__ float s_l[SS][SS + 1];
  __shared__ float av2[HIDD];
  const int t = threadIdx.x;
  const int bid = blockIdx.x;  // b*H + h
  const int b = bid >> 4;
  const int h = bid & (HH - 1);

  const float* pqg = preq_ws + ((size_t)b * SS * HH + h) * HIDD;
  const float* pkg = prek_ws + ((size_t)b * SS * HH + h) * HIDD;
  for (int idx = t; idx < SS * 32; idx += 1024) {
    const int ii = idx >> 5;
    const int c4 = (idx & 31) << 2;
    const f32x4 vq = *(const f32x4*)(pqg + (size_t)ii * HH * HIDD + c4);
    const f32x4 vk = *(const f32x4*)(pkg + (size_t)ii * HH * HIDD + c4);
    *(f32x4*)&pk_l[ii][c4] = vk;
    pqT[c4 + 0][ii] = vq[0];
    pqT[c4 + 1][ii] = vq[1];
    pqT[c4 + 2][ii] = vq[2];
    pqT[c4 + 3][ii] = vq[3];
  }
  if (t < HIDD) av2[t] = 2.0f * attnv[t];
  __syncthreads();

  const int i = t & 63;
  const int g = t >> 6;
  const int j0 = g << 2;
  float acc0 = 0.f, acc1 = 0.f, acc2 = 0.f, acc3 = 0.f;
  for (int c = 0; c < HIDD; c += 4) {
    const float q0 = pqT[c + 0][i];
    const float q1 = pqT[c + 1][i];
    const float q2 = pqT[c + 2][i];
    const float q3 = pqT[c + 3][i];
    const f32x4 a4 = *(const f32x4*)&av2[c];
    const f32x4 k0 = *(const f32x4*)&pk_l[j0 + 0][c];
    const f32x4 k1 = *(const f32x4*)&pk_l[j0 + 1][c];
    const f32x4 k2 = *(const f32x4*)&pk_l[j0 + 2][c];
    const f32x4 k3 = *(const f32x4*)&pk_l[j0 + 3][c];
#pragma unroll
    for (int u = 0; u < 4; ++u) {
      const float qv = (u == 0 ? q0 : (u == 1 ? q1 : (u == 2 ? q2 : q3)));
      const float avu = a4[u];
      acc0 = fmaf(avu, __builtin_amdgcn_rcpf(__builtin_amdgcn_exp2f(qv + k0[u]) + 1.f), acc0);
      acc1 = fmaf(avu, __builtin_amdgcn_rcpf(__builtin_amdgcn_exp2f(qv + k1[u]) + 1.f), acc1);
      acc2 = fmaf(avu, __builtin_amdgcn_rcpf(__builtin_amdgcn_exp2f(qv + k2[u]) + 1.f), acc2);
      acc3 = fmaf(avu, __builtin_amdgcn_rcpf(__builtin_amdgcn_exp2f(qv + k3[u]) + 1.f), acc3);
    }
  }
  s_l[i][j0 + 0] = -acc0;
  s_l[i][j0 + 1] = -acc1;
  s_l[i][j0 + 2] = -acc2;
  s_l[i][j0 + 3] = -acc3;
  __syncthreads();

  // softmax over j, 16 threads per row
  const int ri = t >> 4;
  const int l16 = t & 15;
  const float v0 = s_l[ri][l16];
  const float v1 = s_l[ri][l16 + 16];
  const float v2 = s_l[ri][l16 + 32];
  const float v3 = s_l[ri][l16 + 48];
  float m = fmaxf(fmaxf(v0, v1), fmaxf(v2, v3));
#pragma unroll
  for (int o = 8; o >= 1; o >>= 1) m = fmaxf(m, __shfl_xor(m, o, 16));
  const float L2E = 1.4426950408889634f;
  const float p0 = __builtin_amdgcn_exp2f((v0 - m) * L2E);
  const float p1 = __builtin_amdgcn_exp2f((v1 - m) * L2E);
  const float p2 = __builtin_amdgcn_exp2f((v2 - m) * L2E);
  const float p3 = __builtin_amdgcn_exp2f((v3 - m) * L2E);
  float sum = p0 + p1 + p2 + p3;
#pragma unroll
  for (int o = 8; o >= 1; o >>= 1) sum += __shfl_xor(sum, o, 16);
  const float rs = __builtin_amdgcn_rcpf(sum);
  float* wrow = w_ws + ((size_t)bid * SS + ri) * SS;  // [b][h][i][j]
  wrow[l16] = p0 * rs;
  wrow[l16 + 16] = p1 * rs;
  wrow[l16 + 32] = p2 * rs;
  wrow[l16 + 48] = p3 * rs;
}

// ---------------- Kernel C: ctx (contract heads) + final GEMV ---------------
// grid = B*S/RC = 256, block = 512.
// GEMV phase: thread t -> e = t&255, half = t>>8; owns RC=4 rows over half
// the m range. ctx reads are wave-uniform b128 broadcasts (1 per 16 FMA).
__global__ __launch_bounds__(512) void kC(
    const float* __restrict__ w_ws, const float* __restrict__ v_ws,
    const float* __restrict__ Wfc, const float* __restrict__ bfc,
    float* __restrict__ out)
{
  __shared__ float w_l[RC][HH * SS];    // [r][h*64+j]
  __shared__ float v_l[RC][EE];         // [r][h*16+d]
  __shared__ float ctx_l[RC][SS * DD];  // [r][j*16+d] == [r][m]
  __shared__ float red[RC][EE];
  const int t = threadIdx.x;
  const int row0 = blockIdx.x * RC;

  for (int idx = t; idx < RC * HH * SS; idx += 512) {
    const int r = idx >> 10;
    const int rem = idx & 1023;
    const int hh = rem >> 6;
    const int j = rem & 63;
    const int row = row0 + r;
    const int b = row >> 6;
    const int i = row & 63;
    w_l[r][rem] = w_ws[(size_t)b * HH * SS * SS + (size_t)hh * SS * SS + (size_t)i * SS + j];
  }
  for (int idx = t; idx < RC * EE; idx += 512)
    v_l[idx >> 8][idx & 255] = v_ws[(size_t)(row0 + (idx >> 8)) * EE + (idx & 255)];
  __syncthreads();

  // ctx[r][j*16+d] = sum_h w[r][h*64+j] * v[r][h*16+d]
  for (int idx = t; idx < RC * SS * DD; idx += 512) {
    const int r = idx >> 10;
    const int jd = idx & 1023;
    const int j = jd >> 4;
    const int d = jd & 15;
    float s = 0.f;
#pragma unroll
    for (int hh = 0; hh < HH; ++hh) s += w_l[r][hh * SS + j] * v_l[r][hh * DD + d];
    ctx_l[r][jd] = s;
  }
  __syncthreads();

  const int e = t & 255;
  const int half = t >> 8;
  const float* wf = Wfc + (size_t)e * (SS * DD) + half * 512;
  const float* cl = &ctx_l[0][half * 512];
  float acc[RC];
#pragma unroll
  for (int r = 0; r < RC; ++r) acc[r] = 0.f;
#pragma unroll 4
  for (int mm = 0; mm < 512; mm += 4) {
    const f32x4 w4 = *(const f32x4*)(wf + mm);
#pragma unroll
    for (int r = 0; r < RC; ++r) {
      const f32x4 c4 = *(const f32x4*)(cl + r * (SS * DD) + mm);
      acc[r] += c4[0] * w4[0] + c4[1] * w4[1] + c4[2] * w4[2] + c4[3] * w4[3];
    }
  }
  if (half == 1) {
#pragma unroll
    for (int r = 0; r < RC; ++r) red[r][e] = acc[r];
  }
  __syncthreads();
  if (half == 0) {
    const float bias = bfc[e];
#pragma unroll
    for (int r = 0; r < RC; ++r)
      out[(size_t)(row0 + r) * EE + e] = acc[r] + red[r][e] + bias;
  }
}

extern "C" void kernel_launch(void* const* d_in, const int* in_sizes, int n_in,
                              void* d_out, int out_size, void* d_ws, size_t ws_size,
                              hipStream_t stream) {
  const float* x   = (const float*)d_in[0];
  const float* Wq  = (const float*)d_in[1];
  const float* bq  = (const float*)d_in[2];
  const float* Wk  = (const float*)d_in[3];
  const float* bk  = (const float*)d_in[4];
  const float* Wv  = (const float*)d_in[5];
  const float* bv  = (const float*)d_in[6];
  const float* Wa  = (const float*)d_in[7];
  const float* ba  = (const float*)d_in[8];
  const float* av  = (const float*)d_in[9];
  const float* Wfc = (const float*)d_in[10];
  const float* bfc = (const float*)d_in[11];

  float* ws = (float*)d_ws;
  float* v_ws    = ws;                                      // 262144 f32
  float* preq_ws = v_ws + (size_t)BB * SS * EE;             // 2097152 f32
  float* prek_ws = preq_ws + (size_t)BB * SS * HH * HIDD;   // 2097152 f32
  float* w_ws    = prek_ws + (size_t)BB * SS * HH * HIDD;   // 1048576 f32

  hipLaunchKernelGGL(kA, dim3(BB * SS / RA), dim3(768), 0, stream,
                     x, Wq, bq, Wk, bk, Wv, bv, Wa, ba, v_ws, preq_ws, prek_ws);
  hipLaunchKernelGGL(kB, dim3(BB * HH), dim3(1024), 0, stream,
                     preq_ws, prek_ws, av, w_ws);
  hipLaunchKernelGGL(kC, dim3(BB * SS / RC), dim3(512), 0, stream,
                     w_ws, v_ws, Wfc, bfc, (float*)d_out);
}

// Round 9
// 129.388 us; speedup vs baseline: 1.5027x; 1.4000x over previous
//
#include <hip/hip_runtime.h>

#define BB 16
#define SS 64
#define HH 16
#define DD 16
#define EE 256
#define HIDD 128

typedef float f32x4 __attribute__((ext_vector_type(4)));

#define K2CONST 2.8853900817779268f  /* 2*log2(e) */
#define L2E 1.4426950408889634f

// ---- K1 shared-memory layout (floats) ----
// W slices padded to stride 260 (16B-aligned rows, conflict-free 8-lane spread)
#define WQ_OFF 0            // 16*260 = 4160
#define WK_OFF 4160
#define WV_OFF 8320
#define WA_OFF 12480        // 128*36 = 4608 (stride 36: rows 16B-aligned)
#define EQT_OFF 17088       // [c][i] stride 65 -> 128*65 = 8320
#define EKL_OFF 25408       // [j][c] stride 132 -> 64*132 = 8448
#define QL_OFF 33856        // [i][d] stride 20 -> 64*20 = 1280
#define KL_OFF 35136        // 1280
#define AV2_OFF 36416       // 128
#define KBA_OFF 36544       // 128
#define SM_TOT 36672        // 146.7 KB
#define SL_OFF 0            // s_l[i][j] stride 65 (4160 f) overlays WQ (phase3+)

// ---------------- K1: per (b,h): q/k/v + pre + scores + softmax -------------
// grid = B*H = 256, block = 512
__global__ __launch_bounds__(512) void k1(
    const float* __restrict__ x,
    const float* __restrict__ Wq, const float* __restrict__ bq,
    const float* __restrict__ Wk, const float* __restrict__ bk,
    const float* __restrict__ Wv, const float* __restrict__ bv,
    const float* __restrict__ Wa, const float* __restrict__ ba,
    const float* __restrict__ attnv,
    float* __restrict__ v_ws, float* __restrict__ w_ws)
{
  __shared__ float sm[SM_TOT];
  const int t = threadIdx.x;
  const int bid = blockIdx.x;
  const int b = bid >> 4;
  const int h = bid & (HH - 1);

  // ---- stage: W slices (rows h*16..h*16+15), Wa, av, ba ----
  for (int idx = t; idx < 16 * EE; idx += 512) {
    const int r = idx >> 8;
    const int e = idx & 255;
    const size_t g = (size_t)(h * DD + r) * EE + e;
    sm[WQ_OFF + r * 260 + e] = Wq[g];
    sm[WK_OFF + r * 260 + e] = Wk[g];
    sm[WV_OFF + r * 260 + e] = Wv[g];
  }
  for (int idx = t; idx < HIDD * 2 * DD; idx += 512)
    sm[WA_OFF + (idx >> 5) * 36 + (idx & 31)] = Wa[idx];
  if (t < HIDD) {
    sm[AV2_OFF + t] = 2.0f * attnv[t];
    sm[KBA_OFF + t] = K2CONST * ba[t];
  }
  __syncthreads();

  // ---- phase1: q,k,v for row i, cols d and d+8 (head h) ----
  {
    const int i = t >> 3;
    const int dl = t & 7;
    float aq0 = 0.f, aq1 = 0.f, ak0 = 0.f, ak1 = 0.f, av0 = 0.f, av1 = 0.f;
    const float* xr = x + (size_t)(b * SS + i) * EE;
    const float* wq0 = &sm[WQ_OFF + dl * 260];
    const float* wq1 = &sm[WQ_OFF + (dl + 8) * 260];
    const float* wk0 = &sm[WK_OFF + dl * 260];
    const float* wk1 = &sm[WK_OFF + (dl + 8) * 260];
    const float* wv0 = &sm[WV_OFF + dl * 260];
    const float* wv1 = &sm[WV_OFF + (dl + 8) * 260];
#pragma unroll 4
    for (int e = 0; e < EE; e += 4) {
      const f32x4 x4 = *(const f32x4*)(xr + e);
      const f32x4 q04 = *(const f32x4*)(wq0 + e);
      const f32x4 q14 = *(const f32x4*)(wq1 + e);
      const f32x4 k04 = *(const f32x4*)(wk0 + e);
      const f32x4 k14 = *(const f32x4*)(wk1 + e);
      const f32x4 v04 = *(const f32x4*)(wv0 + e);
      const f32x4 v14 = *(const f32x4*)(wv1 + e);
#pragma unroll
      for (int u = 0; u < 4; ++u) {
        aq0 = fmaf(x4[u], q04[u], aq0);
        aq1 = fmaf(x4[u], q14[u], aq1);
        ak0 = fmaf(x4[u], k04[u], ak0);
        ak1 = fmaf(x4[u], k14[u], ak1);
        av0 = fmaf(x4[u], v04[u], av0);
        av1 = fmaf(x4[u], v14[u], av1);
      }
    }
    sm[QL_OFF + i * 20 + dl]     = aq0 + bq[h * DD + dl];
    sm[QL_OFF + i * 20 + dl + 8] = aq1 + bq[h * DD + dl + 8];
    sm[KL_OFF + i * 20 + dl]     = ak0 + bk[h * DD + dl];
    sm[KL_OFF + i * 20 + dl + 8] = ak1 + bk[h * DD + dl + 8];
    v_ws[(size_t)(b * SS + i) * EE + h * DD + dl]     = av0 + bv[h * DD + dl];
    v_ws[(size_t)(b * SS + i) * EE + h * DD + dl + 8] = av1 + bv[h * DD + dl + 8];
  }
  __syncthreads();

  // ---- phase2: eq[c][i] = exp2(K2*(q.Wa[:, :16] + ba)), ek[i][c] = exp2(K2*(k.Wa[:,16:])) ----
  {
    const int i = t >> 3;
    const int cg = t & 7;
    f32x4 q4[4], k4[4];
#pragma unroll
    for (int u = 0; u < 4; ++u) {
      q4[u] = *(const f32x4*)&sm[QL_OFF + i * 20 + u * 4];
      k4[u] = *(const f32x4*)&sm[KL_OFF + i * 20 + u * 4];
    }
#pragma unroll 2
    for (int jj = 0; jj < 16; ++jj) {
      const int c = cg + 8 * jj;
      const float* war = &sm[WA_OFF + c * 36];
      float sq = 0.f, sk = 0.f;
#pragma unroll
      for (int u = 0; u < 4; ++u) {
        const f32x4 a4 = *(const f32x4*)(war + u * 4);
        const f32x4 b4 = *(const f32x4*)(war + 16 + u * 4);
#pragma unroll
        for (int w = 0; w < 4; ++w) {
          sq = fmaf(q4[u][w], a4[w], sq);
          sk = fmaf(k4[u][w], b4[w], sk);
        }
      }
      const float eq = __builtin_amdgcn_exp2f(fmaf(K2CONST, sq, sm[KBA_OFF + c]));
      const float ek = __builtin_amdgcn_exp2f(K2CONST * sk);
      sm[EQT_OFF + c * 65 + i] = eq;
      sm[EKL_OFF + i * 132 + c] = ek;
    }
  }
  __syncthreads();

  // ---- phase3: scores. s(i,j) = -sum_c av2[c] * rcp(eq[c][i]*ek[j][c] + 1) ----
  {
    const int i = t & 63;
    const int j0 = (t >> 6) << 3;
    float acc[8];
#pragma unroll
    for (int jj = 0; jj < 8; ++jj) acc[jj] = 0.f;
#pragma unroll 2
    for (int c = 0; c < HIDD; c += 4) {
      const f32x4 a4 = *(const f32x4*)&sm[AV2_OFF + c];
      float eq[4];
#pragma unroll
      for (int u = 0; u < 4; ++u) eq[u] = sm[EQT_OFF + (c + u) * 65 + i];
      f32x4 ek[8];
#pragma unroll
      for (int jj = 0; jj < 8; ++jj) ek[jj] = *(const f32x4*)&sm[EKL_OFF + (j0 + jj) * 132 + c];
#pragma unroll
      for (int u = 0; u < 4; ++u) {
#pragma unroll
        for (int jj = 0; jj < 8; ++jj) {
          const float r = __builtin_amdgcn_rcpf(fmaf(eq[u], ek[jj][u], 1.f));
          acc[jj] = fmaf(a4[u], r, acc[jj]);
        }
      }
    }
#pragma unroll
    for (int jj = 0; jj < 8; ++jj) sm[SL_OFF + i * 65 + j0 + jj] = -acc[jj];
  }
  __syncthreads();

  // ---- phase4: softmax over j, write w_ws[b][h][i][j] ----
  {
    const int row = t >> 3;
    const int l8 = t & 7;
    float v[8];
#pragma unroll
    for (int jj = 0; jj < 8; ++jj) v[jj] = sm[SL_OFF + row * 65 + l8 * 8 + jj];
    float m = v[0];
#pragma unroll
    for (int jj = 1; jj < 8; ++jj) m = fmaxf(m, v[jj]);
    m = fmaxf(m, __shfl_xor(m, 1));
    m = fmaxf(m, __shfl_xor(m, 2));
    m = fmaxf(m, __shfl_xor(m, 4));
    float p[8], sum = 0.f;
#pragma unroll
    for (int jj = 0; jj < 8; ++jj) {
      p[jj] = __builtin_amdgcn_exp2f((v[jj] - m) * L2E);
      sum += p[jj];
    }
    sum += __shfl_xor(sum, 1);
    sum += __shfl_xor(sum, 2);
    sum += __shfl_xor(sum, 4);
    const float rs = __builtin_amdgcn_rcpf(sum);
    float* wr = w_ws + ((size_t)bid * SS + row) * SS + l8 * 8;
    f32x4 o0, o1;
#pragma unroll
    for (int u = 0; u < 4; ++u) { o0[u] = p[u] * rs; o1[u] = p[4 + u] * rs; }
    *(f32x4*)(wr) = o0;
    *(f32x4*)(wr + 4) = o1;
  }
}

// ---------------- K2: ctx (contract heads) + fc GEMV ------------------------
// grid = B*S/4 = 256, block = 512. fc: lane = 16 k-chunks x 4 e-groups,
// coalesced Wfc segments + shfl reduce.
__global__ __launch_bounds__(512) void k2(
    const float* __restrict__ w_ws, const float* __restrict__ v_ws,
    const float* __restrict__ Wfc, const float* __restrict__ bfc,
    float* __restrict__ out)
{
  __shared__ float wl[4 * HH * SS];   // [r][h][j] 4096
  __shared__ float vl[4 * 272];       // [r][h*17+d]
  __shared__ float ctx[4 * 1024];     // [r][j*16+d]
  const int t = threadIdx.x;
  const int row0 = blockIdx.x * 4;
  const int b = row0 >> 6;
  const int i0 = row0 & 63;

#pragma unroll
  for (int u = 0; u < 8; ++u) {
    const int idx = t + 512 * u;
    const int r = idx >> 10;
    const int rem = idx & 1023;
    const int h = rem >> 6;
    const int j = rem & 63;
    wl[idx] = w_ws[(((size_t)b * HH + h) * SS + i0 + r) * SS + j];
  }
#pragma unroll
  for (int u = 0; u < 2; ++u) {
    const int idx = t + 512 * u;
    const int r = idx >> 8;
    const int rem = idx & 255;
    vl[r * 272 + (rem >> 4) * 17 + (rem & 15)] = v_ws[(size_t)(row0 + r) * EE + rem];
  }
  __syncthreads();

  // ctx[r][j*16+d] = sum_h wl[r][h][j] * vl[r][h][d]
#pragma unroll
  for (int u = 0; u < 8; ++u) {
    const int o = t + 512 * u;
    const int r = o >> 10;
    const int rem = o & 1023;
    const int j = rem >> 4;
    const int d = rem & 15;
    float s = 0.f;
#pragma unroll
    for (int h = 0; h < HH; ++h)
      s = fmaf(wl[r * 1024 + h * SS + j], vl[r * 272 + h * 17 + d], s);
    ctx[o] = s;
  }
  __syncthreads();

  // fc: out[row0+r][e] = ctx[r] . Wfc[e] + bfc[e]
  {
    const int wave = t >> 6;
    const int lane = t & 63;
    const int kg = lane & 15;
    const int eg = lane >> 4;
#pragma unroll 2
    for (int outer = 0; outer < 8; ++outer) {
      const int e = wave * 32 + outer * 4 + eg;
      const float* wfr = Wfc + (size_t)e * (SS * DD);
      float a0 = 0.f, a1 = 0.f, a2 = 0.f, a3 = 0.f;
#pragma unroll 4
      for (int p = 0; p < 16; ++p) {
        const int k0 = p * 64 + kg * 4;
        const f32x4 wf = *(const f32x4*)(wfr + k0);
        const f32x4 c0 = *(const f32x4*)(ctx + k0);
        const f32x4 c1 = *(const f32x4*)(ctx + 1024 + k0);
        const f32x4 c2 = *(const f32x4*)(ctx + 2048 + k0);
        const f32x4 c3 = *(const f32x4*)(ctx + 3072 + k0);
#pragma unroll
        for (int u = 0; u < 4; ++u) {
          a0 = fmaf(wf[u], c0[u], a0);
          a1 = fmaf(wf[u], c1[u], a1);
          a2 = fmaf(wf[u], c2[u], a2);
          a3 = fmaf(wf[u], c3[u], a3);
        }
      }
#pragma unroll
      for (int msk = 1; msk <= 8; msk <<= 1) {
        a0 += __shfl_xor(a0, msk);
        a1 += __shfl_xor(a1, msk);
        a2 += __shfl_xor(a2, msk);
        a3 += __shfl_xor(a3, msk);
      }
      if (kg == 0) {
        const float bias = bfc[e];
        out[(size_t)(row0 + 0) * EE + e] = a0 + bias;
        out[(size_t)(row0 + 1) * EE + e] = a1 + bias;
        out[(size_t)(row0 + 2) * EE + e] = a2 + bias;
        out[(size_t)(row0 + 3) * EE + e] = a3 + bias;
      }
    }
  }
}

extern "C" void kernel_launch(void* const* d_in, const int* in_sizes, int n_in,
                              void* d_out, int out_size, void* d_ws, size_t ws_size,
                              hipStream_t stream) {
  const float* x   = (const float*)d_in[0];
  const float* Wq  = (const float*)d_in[1];
  const float* bq  = (const float*)d_in[2];
  const float* Wk  = (const float*)d_in[3];
  const float* bk  = (const float*)d_in[4];
  const float* Wv  = (const float*)d_in[5];
  const float* bv  = (const float*)d_in[6];
  const float* Wa  = (const float*)d_in[7];
  const float* ba  = (const float*)d_in[8];
  const float* av  = (const float*)d_in[9];
  const float* Wfc = (const float*)d_in[10];
  const float* bfc = (const float*)d_in[11];

  float* ws = (float*)d_ws;
  float* v_ws = ws;                                 // B*S*E   = 262144 f32
  float* w_ws = v_ws + (size_t)BB * SS * EE;        // B*H*S*S = 1048576 f32

  hipLaunchKernelGGL(k1, dim3(BB * HH), dim3(512), 0, stream,
                     x, Wq, bq, Wk, bk, Wv, bv, Wa, ba, av, v_ws, w_ws);
  hipLaunchKernelGGL(k2, dim3(BB * SS / 4), dim3(512), 0, stream,
                     w_ws, v_ws, Wfc, bfc, (float*)d_out);
}